// Round 17
// baseline (255.797 us; speedup 1.0000x reference)
//
#include <hip/hip_runtime.h>
#include <hip/hip_bf16.h>

#define BB 8
#define CC_ 256
#define HH 56
#define WW 56
#define HWSZ (HH*WW)
#define RR_ 2
#define HID 64
#define FPR ((size_t)8*58*58*256)   // padded NHWC region elements
#define HPR ((size_t)8*58*58*64)    // padded NHWC hidden elements (per region)
#define NPIX ((size_t)BB*HWSZ)      // 25088

typedef __hip_bfloat16 bf16;
typedef __attribute__((ext_vector_type(8))) short short8;
typedef __attribute__((ext_vector_type(4))) short short4_t;
typedef __attribute__((ext_vector_type(4))) float f32x4;

struct Tap { int o00, o01, o10, o11; float w00, w01, w10, w11; };  // 32B

__device__ __forceinline__ float b2f(bf16 v){ return __bfloat162float(v); }
__device__ __forceinline__ bf16 f2b(float v){ return __float2bfloat16(v); }
__device__ __forceinline__ float bs2f(short s){ return __uint_as_float(((unsigned)(unsigned short)s)<<16); }

// K1: fused decoupler (1x1 conv + softmax) + NHWC bf16 pack of both F_i regions
// + 8-wide row partial sums for the AKG pool. bprep fused as tail blocks 448..673
// (verified neutral-or-better round 15). Round-16's cooperative pw2+BN fusion REVERTED:
// hipLaunchCooperativeKernel is silently dropped under the harness's graph capture (out
// never written; absmax 5.72 = max |z| of the untouched zero buffer).
__global__ __launch_bounds__(256) void k_scalepack(const float* __restrict__ F, const float* __restrict__ dec_w,
                                                   const float* __restrict__ dec_b,
                                                   bf16* __restrict__ Fp, float* __restrict__ rowsum,
                                                   const float* __restrict__ w1, const float* __restrict__ wpw,
                                                   const float* __restrict__ wc2,
                                                   bf16* __restrict__ Bp, bf16* __restrict__ Bpw,
                                                   bf16* __restrict__ Bc){
    __shared__ float lds_f[256][57];
    __shared__ float lw0[256], lw1[256];
    __shared__ float ls0[56], ls1[56];
    int bx = blockIdx.x;
    int tid = threadIdx.x;
    if (bx >= 448){
        // ---- bprep tail blocks: id = (bx-448)*4 + (tid>>6), lane L = tid&63 ----
        int id = (bx - 448)*4 + (tid >> 6);
        int L = tid & 63;
        if (id < 576){
            int nt = id & 3; id >>= 2; int icc = id & 7; id >>= 3; int t = id % 9; int r = id / 9;
            int oc = nt*16 + (L&15);
            const float* wr = w1 + (size_t)r*HID*CC_*9;
            bf16* out = Bp + (((((size_t)r*9 + t)*8 + icc)*4 + nt)*64 + L)*8;
            #pragma unroll
            for (int j = 0; j < 8; ++j){
                int ic = icc*32 + (L>>4)*8 + j;
                out[j] = f2b(wr[((size_t)oc*CC_ + ic)*9 + t]);
            }
        } else if (id < 832){
            id -= 576;                     // 256
            int kk = id >> 4, nt = id & 15;
            int oc = nt*16 + (L&15);
            bf16* out = Bpw + (((size_t)(kk*16+nt))*64 + L)*8;
            #pragma unroll
            for (int j = 0; j < 8; ++j){
                int ic = kk*32 + (L>>4)*8 + j;
                out[j] = f2b(wpw[(size_t)oc*512 + ic]);
            }
        } else if (id < 904){
            id -= 832;                     // 72
            int nt = id & 1; id >>= 1; int ks = id % 18; int r = id / 18;
            int t = ks >> 1, chunk = ks & 1;
            int oc = nt*16 + (L&15);
            const float* wr = wc2 + (size_t)r*18*HID*9;
            bf16* out = Bc + ((((size_t)r*18 + ks)*2 + nt)*64 + L)*8;
            #pragma unroll
            for (int j = 0; j < 8; ++j){
                int ic = chunk*32 + (L>>4)*8 + j;
                out[j] = (oc < 18) ? f2b(wr[((size_t)oc*HID + ic)*9 + t]) : f2b(0.f);
            }
        }
        return;
    }
    int b = bx/HH, gy = bx%HH;
    lw0[tid] = dec_w[tid]; lw1[tid] = dec_w[CC_+tid];
    const float* Fb = F + (size_t)b*CC_*HWSZ + gy*WW;
    for (int it = 0; it < 56; ++it){
        int idx = it*256 + tid;
        int c = idx / 56, x = idx - c*56;
        lds_f[c][x] = Fb[(size_t)c*HWSZ + x];
    }
    __syncthreads();
    if (tid < 56){
        float a0 = dec_b[0], a1 = dec_b[1];
        for (int c = 0; c < CC_; ++c){ float v = lds_f[c][tid]; a0 += v*lw0[c]; a1 += v*lw1[c]; }
        float m = fmaxf(a0,a1);
        float e0 = __expf(a0-m), e1 = __expf(a1-m);
        float inv = 1.0f/(e0+e1);
        ls0[tid] = 1.0f + e0*inv; ls1[tid] = 1.0f + e1*inv;
    }
    __syncthreads();
    bf16 z = f2b(0.f);
    for (int r = 0; r < 2; ++r){
        const float* lsr = r ? ls1 : ls0;
        bf16* slab = Fp + (size_t)r*FPR + (size_t)b*58*58*256;
        bf16* dst = slab + ((size_t)(gy+1)*58 + 1)*256 + tid;
        for (int x2 = 0; x2 < 56; ++x2) dst[(size_t)x2*256] = f2b(lds_f[tid][x2] * lsr[x2]);
        // AKG pool row partials: rowsum[((r*8+b)*56+gy)*7+v)*256 + c]
        float* rs = rowsum + ((((size_t)(r*8+b)*56 + gy)*7))*256 + tid;
        #pragma unroll
        for (int v = 0; v < 7; ++v){
            float sum = 0.f;
            #pragma unroll
            for (int k = 0; k < 8; ++k) sum += lds_f[tid][v*8+k] * lsr[v*8+k];
            rs[(size_t)v*256] = sum;
        }
        bf16* rowp = slab + (size_t)(gy+1)*58*256;
        rowp[tid] = z;                 // col 0
        rowp[57*256 + tid] = z;        // col 57
        if (gy == 0){ for (int cidx = 0; cidx < 58; ++cidx) slab[(size_t)cidx*256 + tid] = z; }
        if (gy == 55){ bf16* r57 = slab + (size_t)57*58*256;
                       for (int cidx = 0; cidx < 58; ++cidx) r57[(size_t)cidx*256 + tid] = z; }
    }
}

// K2: conv3x3 256->64 MFMA implicit GEMM. v10 EXACT (round-10/13/15 verified ~42.5us):
// full-A LDS staging (118KB A + 32KB B), pure ds_read+MFMA compute, B reg-prefetch per tap.
__global__ __launch_bounds__(256, 1) void k_conv1(const bf16* __restrict__ Fp, const bf16* __restrict__ Bp,
                                                  const float* __restrict__ bias, bf16* __restrict__ hp){
    __shared__ __attribute__((aligned(16))) bf16 alds[4*58*264];   // 122496 B: rows y0..y0+3, x-stride 264
    __shared__ __attribute__((aligned(16))) bf16 blds[16384];      // 32KB: one B-tap
    int bx = blockIdx.x;
    int x8 = bx & 7, g = bx >> 3;
    int r = x8 >> 2;                       // XCD = r*4 + (b&3): one region per 4-XCD group
    int b = (g/28)*4 + (x8 & 3);
    int yp = g % 28;
    int y0 = yp*2;
    int tid = threadIdx.x; int wave = tid>>6, lane = tid&63;
    int m = lane&15, q = lane>>4;
    int x0 = (wave==3) ? 40 : wave*16;
    f32x4 acc[2][4];
    #pragma unroll
    for (int i=0;i<2;++i)
        #pragma unroll
        for (int j=0;j<4;++j) acc[i][j] = (f32x4){0,0,0,0};
    const bf16* Fb = Fp + (size_t)r*FPR + ((size_t)b*58*58)*256;
    const bf16* Bpr = Bp + (size_t)r*9*16384;    // per-tap stride 16384 elems (32KB)
    // B tap-0 prefetch into regs
    short8 pf[8];
    #pragma unroll
    for (int j = 0; j < 8; ++j) pf[j] = *(const short8*)(Bpr + (size_t)(j*256 + tid)*8);
    // A stage: 4 contiguous padded rows = 59392 elems = 29 x 2048; batched 8 loads then 8 writes
    const bf16* FbA = Fb + (size_t)y0*58*256;
    for (int kb = 0; kb < 4; ++kb){
        short8 v[8];
        #pragma unroll
        for (int j = 0; j < 8; ++j){
            int k = kb*8 + j;
            if (k < 29) v[j] = *(const short8*)(FbA + (size_t)k*2048 + tid*8);
        }
        #pragma unroll
        for (int j = 0; j < 8; ++j){
            int k = kb*8 + j;
            if (k < 29){
                int e = k*2048 + tid*8;
                int xl = e >> 8, c = e & 255;
                int row = xl / 58, x = xl - row*58;
                *(short8*)&alds[row*15312 + x*264 + c] = v[j];
            }
        }
    }
    #pragma unroll 1
    for (int t = 0; t < 9; ++t){
        __syncthreads();                         // (a) prev-tap B reads done; A-stage drained at t=0
        #pragma unroll
        for (int j = 0; j < 8; ++j) *(short8*)&blds[(j*256 + tid)*8] = pf[j];
        __syncthreads();                         // (b) staged tap visible
        if (t < 8){                              // next tap's B; lands during compute
            const bf16* src = Bpr + (size_t)(t+1)*16384;
            #pragma unroll
            for (int j = 0; j < 8; ++j) pf[j] = *(const short8*)(src + (size_t)(j*256 + tid)*8);
        }
        int ty = t/3, tx = t%3;
        int abase = ty*15312 + (x0+m+tx)*264 + q*8;
        #pragma unroll
        for (int icc = 0; icc < 8; ++icc){
            short8 a0 = *(const short8*)&alds[abase + icc*32];
            short8 a1 = *(const short8*)&alds[abase + 15312 + icc*32];
            const bf16* bb = &blds[icc*2048 + lane*8];
            short8 b0 = *(const short8*)(bb);
            short8 b1 = *(const short8*)(bb + 512);
            short8 b2 = *(const short8*)(bb + 1024);
            short8 b3 = *(const short8*)(bb + 1536);
            acc[0][0] = __builtin_amdgcn_mfma_f32_16x16x32_bf16(a0, b0, acc[0][0], 0, 0, 0);
            acc[1][0] = __builtin_amdgcn_mfma_f32_16x16x32_bf16(a1, b0, acc[1][0], 0, 0, 0);
            acc[0][1] = __builtin_amdgcn_mfma_f32_16x16x32_bf16(a0, b1, acc[0][1], 0, 0, 0);
            acc[1][1] = __builtin_amdgcn_mfma_f32_16x16x32_bf16(a1, b1, acc[1][1], 0, 0, 0);
            acc[0][2] = __builtin_amdgcn_mfma_f32_16x16x32_bf16(a0, b2, acc[0][2], 0, 0, 0);
            acc[1][2] = __builtin_amdgcn_mfma_f32_16x16x32_bf16(a1, b2, acc[1][2], 0, 0, 0);
            acc[0][3] = __builtin_amdgcn_mfma_f32_16x16x32_bf16(a0, b3, acc[0][3], 0, 0, 0);
            acc[1][3] = __builtin_amdgcn_mfma_f32_16x16x32_bf16(a1, b3, acc[1][3], 0, 0, 0);
        }
    }
    const float* br = bias + r*HID;
    bf16* slab = hp + (size_t)r*HPR + (size_t)b*58*58*64;
    bf16 z = f2b(0.f);
    #pragma unroll
    for (int rr = 0; rr < 2; ++rr){
        int y = y0 + rr;
        bf16* hrow = slab + ((size_t)(y+1)*58 + 1)*64;
        #pragma unroll
        for (int nt = 0; nt < 4; ++nt){
            int oc = nt*16 + m;
            float bv = br[oc];
            #pragma unroll
            for (int r2 = 0; r2 < 4; ++r2){
                int x = x0 + q*4 + r2;
                hrow[(size_t)x*64 + oc] = f2b(fmaxf(acc[rr][nt][r2] + bv, 0.f));
            }
        }
        bf16* rowp = slab + (size_t)(y+1)*58*64;
        if (tid < 64) rowp[tid] = z;
        else if (tid < 128) rowp[57*64 + (tid-64)] = z;
        if (y == 0){ for (int idx = tid; idx < 58*64; idx += 256) slab[idx] = z; }
        if (y == 55){ bf16* r57 = slab + (size_t)57*58*64;
                      for (int idx = tid; idx < 58*64; idx += 256) r57[idx] = z; }
    }
}

// K3: conv2 MFMA implicit GEMM + fused tap-descriptor computation (offsets never touch HBM
// as a separate pass). Grid 896: block = (b, y, r), 18 offset channels -> LDS -> taps.
__global__ __launch_bounds__(256) void k_conv2m(const bf16* __restrict__ hp, const bf16* __restrict__ Bc,
                                                const float* __restrict__ bias, Tap* __restrict__ tap){
    __shared__ float pld[18][56];
    int bx = blockIdx.x; int b = bx & 7; int rid = bx >> 3; int y = rid % 56; int r = rid / 56;
    int tid = threadIdx.x; int wave = tid>>6, lane = tid&63;
    int m = lane&15, q = lane>>4;
    int x0 = (wave==3) ? 40 : wave*16;
    f32x4 acc0 = {0,0,0,0}, acc1 = {0,0,0,0};
    const bf16* Hb = hp + (size_t)r*HPR + ((size_t)b*58 + y)*58*64;
    const bf16* Bcr = Bc + (size_t)r*18*2*64*8;
    #pragma unroll
    for (int t = 0; t < 9; ++t){
        int ty = t/3, tx = t%3;
        const bf16* arow = Hb + ((size_t)ty*58 + (x0+m+tx))*64 + q*8;
        #pragma unroll
        for (int chunk = 0; chunk < 2; ++chunk){
            short8 a = *(const short8*)(arow + chunk*32);
            const bf16* bb = Bcr + (((size_t)(t*2+chunk))*2*64 + lane)*8;
            short8 b0 = *(const short8*)(bb);
            short8 b1 = *(const short8*)(bb + 64*8);
            acc0 = __builtin_amdgcn_mfma_f32_16x16x32_bf16(a, b0, acc0, 0, 0, 0);
            acc1 = __builtin_amdgcn_mfma_f32_16x16x32_bf16(a, b1, acc1, 0, 0, 0);
        }
    }
    const float* br = bias + r*18;
    #pragma unroll
    for (int r2 = 0; r2 < 4; ++r2){
        int x = x0 + q*4 + r2;
        pld[m][x] = acc0[r2] + br[m];                       // overlap x=40..47 writes identical values
        if (m < 2) pld[16+m][x] = acc1[r2] + br[16+m];
    }
    __syncthreads();
    // tap phase: 504 = 9 taps x 56 px
    for (int e = tid; e < 504; e += 256){
        int t = e / 56, x = e % 56;
        int ky = t / 3, kx = t % 3;
        float dy = pld[2*t][x];
        float dx = pld[2*t+1][x];
        float py = (float)(y - 1 + ky) + dy;
        float px = (float)(x - 1 + kx) + dx;
        float y0f = floorf(py), x0f = floorf(px);
        float wy1 = py - y0f, wx1 = px - x0f;
        float wy0 = 1.f - wy1, wx0 = 1.f - wx1;
        float vy0 = (y0f >= 0.f  && y0f <= 55.f) ? 1.f : 0.f;
        float vy1 = (y0f >= -1.f && y0f <= 54.f) ? 1.f : 0.f;
        float vx0 = (x0f >= 0.f  && x0f <= 55.f) ? 1.f : 0.f;
        float vx1 = (x0f >= -1.f && x0f <= 54.f) ? 1.f : 0.f;
        int yy0 = (int)y0f, x0i = (int)x0f;
        int iy0 = min(max(yy0,0),55),   iy1 = min(max(yy0+1,0),55);
        int ix0 = min(max(x0i,0),55),   ix1 = min(max(x0i+1,0),55);
        Tap td;
        td.o00 = ((iy0+1)*58 + ix0+1)*256;
        td.o01 = ((iy0+1)*58 + ix1+1)*256;
        td.o10 = ((iy1+1)*58 + ix0+1)*256;
        td.o11 = ((iy1+1)*58 + ix1+1)*256;
        td.w00 = wy0*wx0*vy0*vx0;
        td.w01 = wy0*wx1*vy0*vx1;
        td.w10 = wy1*wx0*vy1*vx0;
        td.w11 = wy1*wx1*vy1*vx1;
        size_t pid = ((size_t)(r*8 + b))*3136 + y*56 + x;
        tap[pid*9 + t] = td;
    }
}

// K4a: finish AKG pool from row partials: d[7][7] = (1/64)*sum_8gy rowsum; dwconv3x3 pad1 +
// relu; mean/49 -> s[(r*8+b)*256+c]. Grid 16 blocks (r*8+b), 256 thr (c).
__global__ __launch_bounds__(256) void k_akg_s(const float* __restrict__ rowsum, const float* __restrict__ dw,
                                               float* __restrict__ s){
    int rb = blockIdx.x; int r = rb >> 3;
    int c = threadIdx.x;
    const float* rs = rowsum + ((size_t)rb*56*7)*256 + c;
    float d[7][7];
    #pragma unroll
    for (int u = 0; u < 7; ++u)
        #pragma unroll
        for (int v = 0; v < 7; ++v){
            float acc = 0.f;
            #pragma unroll
            for (int k = 0; k < 8; ++k) acc += rs[(size_t)((u*8+k)*7 + v)*256];
            d[u][v] = acc * (1.f/64.f);
        }
    const float* wp = dw + (size_t)r*CC_*9 + c*9;
    float w[9];
    #pragma unroll
    for (int k = 0; k < 9; ++k) w[k] = wp[k];
    float tot = 0.f;
    #pragma unroll
    for (int u = 0; u < 7; ++u)
        #pragma unroll
        for (int v = 0; v < 7; ++v){
            float acc = 0.f;
            #pragma unroll
            for (int ky = 0; ky < 3; ++ky){
                int uu = u+ky-1; if ((unsigned)uu >= 7u) continue;
                #pragma unroll
                for (int kx = 0; kx < 3; ++kx){
                    int vv = v+kx-1; if ((unsigned)vv >= 7u) continue;
                    acc += d[uu][vv]*w[ky*3+kx];
                }
            }
            tot += fmaxf(acc, 0.f);
        }
    s[(size_t)rb*CC_ + c] = tot * (1.f/49.f);
}

// K4b: head matvec + tanh -> Kw (fp32) [r][b][t][c]. Grid 144.
__global__ void k_akg_head(const float* __restrict__ s, const float* __restrict__ hw,
                           const float* __restrict__ hb, float* __restrict__ Kw){
    int gid = blockIdx.x; int r = gid / 72; int id = gid % 72;
    int b = id / 9; int og = id % 9;
    __shared__ float sv[CC_];
    int tid = threadIdx.x; // 256
    sv[tid] = s[(size_t)(r*8+b)*CC_ + tid];
    __syncthreads();
    int o = og*256 + tid;              // o = c*9 + t
    const float* wp = hw + (size_t)r*2304*CC_ + (size_t)o*CC_;
    float acc = hb[(size_t)r*2304 + o];
    for (int c2=0;c2<CC_;++c2) acc += wp[c2]*sv[c2];
    int c = o / 9, t = o - 9*c;
    Kw[((size_t)r*BB + b)*2304 + t*256 + c] = tanhf(acc);
}

// K5: deformable depthwise. v7 EXACT (round-10/13/15 verified ~41-43us): swizzled klds
// (stride 76 floats), wave-coop tap bounce, pixel-pair/wave, 8ch/lane 16B gathers, unroll 3.
__global__ __launch_bounds__(256, 8) void k_deform(const bf16* __restrict__ Fp, const Tap* __restrict__ tap,
                                                   const float* __restrict__ Kw, bf16* __restrict__ outsN){
    __shared__ float klds[2432];                 // swizzled: lane li's tap t at [li*76 + t*8 .. +7]
    __shared__ Tap tlds[4][18];                  // per-wave tap bounce (2 px x 9 taps = 576B)
    int bx = blockIdx.x; int b = bx & 7; int rest = bx >> 3;  // rest = creg*392 + pg
    int pg = rest % 392; int creg = rest / 392;
    int tid = threadIdx.x; int w = tid >> 6, l = tid & 63;
    int wu = __builtin_amdgcn_readfirstlane(w);
    int yx0 = pg*8 + wu*2;                       // wave covers pixels yx0, yx0+1
    size_t slab = (size_t)(creg*8 + b)*3136;
    const float* Kb = Kw + ((size_t)creg*8 + b)*2304;
    // stage Kw swizzled: logical Kb[t*256 + c] -> klds[(c>>3)*76 + t*8 + (c&7)]
    for (int i = tid*4; i < 2304; i += 1024){
        f32x4 v = *(const f32x4*)(Kb + i);
        int t = i >> 8, rem = i & 255;
        *(f32x4*)&klds[(rem >> 3)*76 + t*8 + (rem & 4)] = v;
    }
    // wave-cooperative tap bounce: 18 Taps = 36 x 16B lanes
    if (l < 36)
        *(f32x4*)((char*)&tlds[wu][0] + l*16) =
            *(const f32x4*)((const char*)(tap + (slab + yx0)*9) + l*16);
    __syncthreads();
    int h = l >> 5, li = l & 31;
    const bf16* Fb = Fp + (size_t)creg*FPR + (size_t)b*58*58*256;
    int c0 = li*8;                               // 8 channels per lane
    const float* kl = &klds[li*76];
    const Tap* tw = &tlds[wu][h*9];
    float acc[8];
    #pragma unroll
    for (int j = 0; j < 8; ++j) acc[j] = 0.f;
    #pragma unroll 3
    for (int t = 0; t < 9; ++t){
        Tap d = tw[t];
        short8 f00 = *(const short8*)(Fb + d.o00 + c0);
        short8 f01 = *(const short8*)(Fb + d.o01 + c0);
        short8 f10 = *(const short8*)(Fb + d.o10 + c0);
        short8 f11 = *(const short8*)(Fb + d.o11 + c0);
        f32x4 klo = *(const f32x4*)(kl + t*8);
        f32x4 khi = *(const f32x4*)(kl + t*8 + 4);
        #pragma unroll
        for (int j = 0; j < 4; ++j){
            float v = d.w00*bs2f(f00[j]) + d.w01*bs2f(f01[j]) + d.w10*bs2f(f10[j]) + d.w11*bs2f(f11[j]);
            acc[j] += klo[j]*v;
        }
        #pragma unroll
        for (int j = 4; j < 8; ++j){
            float v = d.w00*bs2f(f00[j]) + d.w01*bs2f(f01[j]) + d.w10*bs2f(f10[j]) + d.w11*bs2f(f11[j]);
            acc[j] += khi[j-4]*v;
        }
    }
    __attribute__((aligned(16))) bf16 tmp[8];
    #pragma unroll
    for (int j = 0; j < 8; ++j) tmp[j] = f2b(acc[j]);
    *(short8*)(outsN + ((size_t)b*HWSZ + yx0 + h)*512 + creg*256 + c0) = *(const short8*)tmp;
}

// K6a: pw2 MFMA GEMM, 2 pixel-tiles per wave, stats via LDS reduce + atomics, O store. Grid 392.
__global__ __launch_bounds__(256) void k_pw2_mstats(const bf16* __restrict__ outsN, const bf16* __restrict__ Bpw,
                                                    const float* __restrict__ bias, float* __restrict__ stats,
                                                    float* __restrict__ O){
    __shared__ float ls[2][2][256];
    int tid = threadIdx.x; int wave = tid>>6, lane = tid&63;
    int pixGroup = wave>>1, ntH = wave&1;
    int m = lane&15, q = lane>>4;
    size_t pb = (size_t)blockIdx.x*64 + pixGroup*32;
    const bf16* Ap0 = outsN + (pb + m)*512 + q*8;
    const bf16* Ap1 = Ap0 + (size_t)16*512;
    f32x4 acc[2][8];
    #pragma unroll
    for (int g=0;g<2;++g)
        #pragma unroll
        for (int i=0;i<8;++i) acc[g][i] = (f32x4){0,0,0,0};
    #pragma unroll 1
    for (int kk = 0; kk < 16; ++kk){
        short8 a0 = *(const short8*)(Ap0 + kk*32);
        short8 a1 = *(const short8*)(Ap1 + kk*32);
        const bf16* Bk = Bpw + (((size_t)kk*16 + ntH*8)*64 + lane)*8;
        #pragma unroll
        for (int nt2 = 0; nt2 < 8; ++nt2){
            short8 b = *(const short8*)(Bk + (size_t)nt2*64*8);
            acc[0][nt2] = __builtin_amdgcn_mfma_f32_16x16x32_bf16(a0, b, acc[0][nt2], 0, 0, 0);
            acc[1][nt2] = __builtin_amdgcn_mfma_f32_16x16x32_bf16(a1, b, acc[1][nt2], 0, 0, 0);
        }
    }
    #pragma unroll
    for (int nt2 = 0; nt2 < 8; ++nt2){
        int oc = ntH*128 + nt2*16 + m;
        float bv = bias[oc];
        float s1 = 0.f, s2 = 0.f;
        #pragma unroll
        for (int g = 0; g < 2; ++g){
            size_t pbg = pb + g*16;
            int b_idx = (int)(pbg / HWSZ);
            int yx0 = (int)(pbg % HWSZ);
            float* op = O + ((size_t)b_idx*CC_ + oc)*HWSZ + yx0 + q*4;
            #pragma unroll
            for (int r = 0; r < 4; ++r){
                float v = acc[g][nt2][r] + bv;
                op[r] = v;
                s1 += v; s2 += v*v;
            }
        }
        s1 += __shfl_down(s1, 32); s1 += __shfl_down(s1, 16);
        s2 += __shfl_down(s2, 32); s2 += __shfl_down(s2, 16);
        if (q == 0){ ls[pixGroup][0][oc] = s1; ls[pixGroup][1][oc] = s2; }
    }
    __syncthreads();
    if (tid < 256){
        atomicAdd(&stats[tid],       ls[0][0][tid] + ls[1][0][tid]);
        atomicAdd(&stats[256 + tid], ls[0][1][tid] + ls[1][1][tid]);
    }
}

// K6b: BN finalize (inline) + apply (elementwise, float4). Grid 6272.
__global__ __launch_bounds__(256) void k_bnapply(const float* __restrict__ O, const float* __restrict__ stats,
                                                 const float* __restrict__ gamma, const float* __restrict__ beta,
                                                 float* __restrict__ out){
    int n = (blockIdx.x*256 + threadIdx.x)*4;   // HWSZ divisible by 4 -> same channel
    int c = (n / HWSZ) % CC_;
    float ninv = 1.f/(float)NPIX;
    float mean = stats[c]*ninv;
    float var = fmaxf(stats[256+c]*ninv - mean*mean, 0.f);
    float rsq = rsqrtf(var + 1e-5f);
    float g = gamma[c], be = beta[c];
    f32x4 v = *(const f32x4*)(O + n);
    f32x4 o;
    #pragma unroll
    for (int j = 0; j < 4; ++j) o[j] = (v[j] - mean)*rsq*g + be;
    *(f32x4*)(out + n) = o;
}

extern "C" void kernel_launch(void* const* d_in, const int* in_sizes, int n_in,
                              void* d_out, int out_size, void* d_ws, size_t ws_size,
                              hipStream_t stream) {
    (void)in_sizes; (void)n_in; (void)out_size; (void)ws_size;
    const float* F_c    = (const float*)d_in[0];
    const float* dec_w  = (const float*)d_in[1];
    const float* dec_b  = (const float*)d_in[2];
    const float* off1_w = (const float*)d_in[3];
    const float* off1_b = (const float*)d_in[4];
    const float* off2_w = (const float*)d_in[5];
    const float* off2_b = (const float*)d_in[6];
    const float* akg_dw = (const float*)d_in[7];
    const float* akg_hw = (const float*)d_in[8];
    const float* akg_hb = (const float*)d_in[9];
    const float* pw2_w  = (const float*)d_in[10];
    const float* pw2_b  = (const float*)d_in[11];
    const float* gamma  = (const float*)d_in[12];
    const float* beta   = (const float*)d_in[13];
    float* out = (float*)d_out;

    char* ws = (char*)d_ws;
    size_t off = 0;
    auto alloc = [&](size_t bytes)->char*{
        char* r = ws + off;
        off = (off + bytes + 255) & ~(size_t)255;
        return r;
    };
    // Workspace ~85 MB.
    bf16*  Fp    = (bf16*) alloc(2*FPR*2);                 // padded NHWC F*sc, both regions
    bf16*  Bp    = (bf16*) alloc((size_t)2*9*16384*2);     // conv1 weight taps (32KB/tap)
    bf16*  Bpw   = (bf16*) alloc((size_t)16*16*64*8*2);    // pw2 weight frags
    bf16*  Bc    = (bf16*) alloc((size_t)2*18*2*64*8*2);   // conv2 weight frags
    float* rowsum= (float*)alloc((size_t)2*8*56*7*256*4);  // AKG pool row partials
    bf16*  hp    = (bf16*) alloc(2*HPR*2);                 // padded NHWC hidden, both regions
    float* s     = (float*)alloc((size_t)2*BB*CC_*4);
    float* Kw    = (float*)alloc((size_t)2*BB*CC_*9*4);
    bf16*  outsN = (bf16*) alloc(NPIX*512*2);              // NHWC, k = creg*256+c
    Tap*   tap   = (Tap*)  alloc((size_t)2*NPIX*9*sizeof(Tap));
    float* stats = (float*)alloc(2*CC_*4);
    // O (fp32, 25.7MB) aliases Fp (27.6MB): Fp is dead after k_deform, O written in k_pw2_mstats.
    float* O = (float*)Fp;

    hipMemsetAsync(stats, 0, 2*CC_*sizeof(float), stream);

    // scalepack + bprep fused (tail blocks 448..673)
    k_scalepack<<<dim3(448 + 226), dim3(256), 0, stream>>>(F_c, dec_w, dec_b, Fp, rowsum,
                                                           off1_w, pw2_w, off2_w, Bp, Bpw, Bc);
    k_conv1<<<dim3(2*BB*28), dim3(256), 0, stream>>>(Fp, Bp, off1_b, hp);
    k_conv2m<<<dim3(2*BB*HH), dim3(256), 0, stream>>>(hp, Bc, off2_b, tap);
    k_akg_s<<<dim3(16), dim3(256), 0, stream>>>(rowsum, akg_dw, s);
    k_akg_head<<<dim3(2*BB*9), dim3(256), 0, stream>>>(s, akg_hw, akg_hb, Kw);
    k_deform<<<dim3(2*BB*392), dim3(256), 0, stream>>>(Fp, tap, Kw, outsN);

    k_pw2_mstats<<<dim3(392), dim3(256), 0, stream>>>(outsN, Bpw, pw2_b, stats, O);
    k_bnapply<<<dim3((int)(NPIX*CC_/1024)), dim3(256), 0, stream>>>(O, stats, gamma, beta, out);
}

// Round 18
// 251.131 us; speedup vs baseline: 1.0186x; 1.0186x over previous
//
#include <hip/hip_runtime.h>
#include <hip/hip_bf16.h>

#define BB 8
#define CC_ 256
#define HH 56
#define WW 56
#define HWSZ (HH*WW)
#define RR_ 2
#define HID 64
#define FPR ((size_t)8*58*58*256)   // padded NHWC region elements
#define HPR ((size_t)8*58*58*64)    // padded NHWC hidden elements (per region)
#define NPIX ((size_t)BB*HWSZ)      // 25088

typedef __hip_bfloat16 bf16;
typedef __attribute__((ext_vector_type(8))) short short8;
typedef __attribute__((ext_vector_type(4))) short short4_t;
typedef __attribute__((ext_vector_type(4))) float f32x4;

struct Tap { int o00, o01, o10, o11; float w00, w01, w10, w11; };  // 32B

__device__ __forceinline__ float b2f(bf16 v){ return __bfloat162float(v); }
__device__ __forceinline__ bf16 f2b(float v){ return __float2bfloat16(v); }
__device__ __forceinline__ float bs2f(short s){ return __uint_as_float(((unsigned)(unsigned short)s)<<16); }

// K1: fused decoupler (1x1 conv + softmax) + NHWC bf16 pack of both F_i regions
// + 8-wide row partial sums for the AKG pool. bprep fused as tail blocks 448..673
// (verified neutral-or-better round 15).
__global__ __launch_bounds__(256) void k_scalepack(const float* __restrict__ F, const float* __restrict__ dec_w,
                                                   const float* __restrict__ dec_b,
                                                   bf16* __restrict__ Fp, float* __restrict__ rowsum,
                                                   const float* __restrict__ w1, const float* __restrict__ wpw,
                                                   const float* __restrict__ wc2,
                                                   bf16* __restrict__ Bp, bf16* __restrict__ Bpw,
                                                   bf16* __restrict__ Bc){
    __shared__ float lds_f[256][57];
    __shared__ float lw0[256], lw1[256];
    __shared__ float ls0[56], ls1[56];
    int bx = blockIdx.x;
    int tid = threadIdx.x;
    if (bx >= 448){
        // ---- bprep tail blocks: id = (bx-448)*4 + (tid>>6), lane L = tid&63 ----
        int id = (bx - 448)*4 + (tid >> 6);
        int L = tid & 63;
        if (id < 576){
            int nt = id & 3; id >>= 2; int icc = id & 7; id >>= 3; int t = id % 9; int r = id / 9;
            int oc = nt*16 + (L&15);
            const float* wr = w1 + (size_t)r*HID*CC_*9;
            bf16* out = Bp + (((((size_t)r*9 + t)*8 + icc)*4 + nt)*64 + L)*8;
            #pragma unroll
            for (int j = 0; j < 8; ++j){
                int ic = icc*32 + (L>>4)*8 + j;
                out[j] = f2b(wr[((size_t)oc*CC_ + ic)*9 + t]);
            }
        } else if (id < 832){
            id -= 576;                     // 256
            int kk = id >> 4, nt = id & 15;
            int oc = nt*16 + (L&15);
            bf16* out = Bpw + (((size_t)(kk*16+nt))*64 + L)*8;
            #pragma unroll
            for (int j = 0; j < 8; ++j){
                int ic = kk*32 + (L>>4)*8 + j;
                out[j] = f2b(wpw[(size_t)oc*512 + ic]);
            }
        } else if (id < 904){
            id -= 832;                     // 72
            int nt = id & 1; id >>= 1; int ks = id % 18; int r = id / 18;
            int t = ks >> 1, chunk = ks & 1;
            int oc = nt*16 + (L&15);
            const float* wr = wc2 + (size_t)r*18*HID*9;
            bf16* out = Bc + ((((size_t)r*18 + ks)*2 + nt)*64 + L)*8;
            #pragma unroll
            for (int j = 0; j < 8; ++j){
                int ic = chunk*32 + (L>>4)*8 + j;
                out[j] = (oc < 18) ? f2b(wr[((size_t)oc*HID + ic)*9 + t]) : f2b(0.f);
            }
        }
        return;
    }
    int b = bx/HH, gy = bx%HH;
    lw0[tid] = dec_w[tid]; lw1[tid] = dec_w[CC_+tid];
    const float* Fb = F + (size_t)b*CC_*HWSZ + gy*WW;
    for (int it = 0; it < 56; ++it){
        int idx = it*256 + tid;
        int c = idx / 56, x = idx - c*56;
        lds_f[c][x] = Fb[(size_t)c*HWSZ + x];
    }
    __syncthreads();
    if (tid < 56){
        float a0 = dec_b[0], a1 = dec_b[1];
        for (int c = 0; c < CC_; ++c){ float v = lds_f[c][tid]; a0 += v*lw0[c]; a1 += v*lw1[c]; }
        float m = fmaxf(a0,a1);
        float e0 = __expf(a0-m), e1 = __expf(a1-m);
        float inv = 1.0f/(e0+e1);
        ls0[tid] = 1.0f + e0*inv; ls1[tid] = 1.0f + e1*inv;
    }
    __syncthreads();
    bf16 z = f2b(0.f);
    for (int r = 0; r < 2; ++r){
        const float* lsr = r ? ls1 : ls0;
        bf16* slab = Fp + (size_t)r*FPR + (size_t)b*58*58*256;
        bf16* dst = slab + ((size_t)(gy+1)*58 + 1)*256 + tid;
        for (int x2 = 0; x2 < 56; ++x2) dst[(size_t)x2*256] = f2b(lds_f[tid][x2] * lsr[x2]);
        // AKG pool row partials: rowsum[((r*8+b)*56+gy)*7+v)*256 + c]
        float* rs = rowsum + ((((size_t)(r*8+b)*56 + gy)*7))*256 + tid;
        #pragma unroll
        for (int v = 0; v < 7; ++v){
            float sum = 0.f;
            #pragma unroll
            for (int k = 0; k < 8; ++k) sum += lds_f[tid][v*8+k] * lsr[v*8+k];
            rs[(size_t)v*256] = sum;
        }
        bf16* rowp = slab + (size_t)(gy+1)*58*256;
        rowp[tid] = z;                 // col 0
        rowp[57*256 + tid] = z;        // col 57
        if (gy == 0){ for (int cidx = 0; cidx < 58; ++cidx) slab[(size_t)cidx*256 + tid] = z; }
        if (gy == 55){ bf16* r57 = slab + (size_t)57*58*256;
                       for (int cidx = 0; cidx < 58; ++cidx) r57[(size_t)cidx*256 + tid] = z; }
    }
}

// K2: conv3x3 256->64 MFMA implicit GEMM. v10 EXACT (round-10/13/15/17 verified ~42.5us):
// full-A LDS staging (118KB A + 32KB B), pure ds_read+MFMA compute, B reg-prefetch per tap.
__global__ __launch_bounds__(256, 1) void k_conv1(const bf16* __restrict__ Fp, const bf16* __restrict__ Bp,
                                                  const float* __restrict__ bias, bf16* __restrict__ hp){
    __shared__ __attribute__((aligned(16))) bf16 alds[4*58*264];   // 122496 B: rows y0..y0+3, x-stride 264
    __shared__ __attribute__((aligned(16))) bf16 blds[16384];      // 32KB: one B-tap
    int bx = blockIdx.x;
    int x8 = bx & 7, g = bx >> 3;
    int r = x8 >> 2;                       // XCD = r*4 + (b&3): one region per 4-XCD group
    int b = (g/28)*4 + (x8 & 3);
    int yp = g % 28;
    int y0 = yp*2;
    int tid = threadIdx.x; int wave = tid>>6, lane = tid&63;
    int m = lane&15, q = lane>>4;
    int x0 = (wave==3) ? 40 : wave*16;
    f32x4 acc[2][4];
    #pragma unroll
    for (int i=0;i<2;++i)
        #pragma unroll
        for (int j=0;j<4;++j) acc[i][j] = (f32x4){0,0,0,0};
    const bf16* Fb = Fp + (size_t)r*FPR + ((size_t)b*58*58)*256;
    const bf16* Bpr = Bp + (size_t)r*9*16384;    // per-tap stride 16384 elems (32KB)
    // B tap-0 prefetch into regs
    short8 pf[8];
    #pragma unroll
    for (int j = 0; j < 8; ++j) pf[j] = *(const short8*)(Bpr + (size_t)(j*256 + tid)*8);
    // A stage: 4 contiguous padded rows = 59392 elems = 29 x 2048; batched 8 loads then 8 writes
    const bf16* FbA = Fb + (size_t)y0*58*256;
    for (int kb = 0; kb < 4; ++kb){
        short8 v[8];
        #pragma unroll
        for (int j = 0; j < 8; ++j){
            int k = kb*8 + j;
            if (k < 29) v[j] = *(const short8*)(FbA + (size_t)k*2048 + tid*8);
        }
        #pragma unroll
        for (int j = 0; j < 8; ++j){
            int k = kb*8 + j;
            if (k < 29){
                int e = k*2048 + tid*8;
                int xl = e >> 8, c = e & 255;
                int row = xl / 58, x = xl - row*58;
                *(short8*)&alds[row*15312 + x*264 + c] = v[j];
            }
        }
    }
    #pragma unroll 1
    for (int t = 0; t < 9; ++t){
        __syncthreads();                         // (a) prev-tap B reads done; A-stage drained at t=0
        #pragma unroll
        for (int j = 0; j < 8; ++j) *(short8*)&blds[(j*256 + tid)*8] = pf[j];
        __syncthreads();                         // (b) staged tap visible
        if (t < 8){                              // next tap's B; lands during compute
            const bf16* src = Bpr + (size_t)(t+1)*16384;
            #pragma unroll
            for (int j = 0; j < 8; ++j) pf[j] = *(const short8*)(src + (size_t)(j*256 + tid)*8);
        }
        int ty = t/3, tx = t%3;
        int abase = ty*15312 + (x0+m+tx)*264 + q*8;
        #pragma unroll
        for (int icc = 0; icc < 8; ++icc){
            short8 a0 = *(const short8*)&alds[abase + icc*32];
            short8 a1 = *(const short8*)&alds[abase + 15312 + icc*32];
            const bf16* bb = &blds[icc*2048 + lane*8];
            short8 b0 = *(const short8*)(bb);
            short8 b1 = *(const short8*)(bb + 512);
            short8 b2 = *(const short8*)(bb + 1024);
            short8 b3 = *(const short8*)(bb + 1536);
            acc[0][0] = __builtin_amdgcn_mfma_f32_16x16x32_bf16(a0, b0, acc[0][0], 0, 0, 0);
            acc[1][0] = __builtin_amdgcn_mfma_f32_16x16x32_bf16(a1, b0, acc[1][0], 0, 0, 0);
            acc[0][1] = __builtin_amdgcn_mfma_f32_16x16x32_bf16(a0, b1, acc[0][1], 0, 0, 0);
            acc[1][1] = __builtin_amdgcn_mfma_f32_16x16x32_bf16(a1, b1, acc[1][1], 0, 0, 0);
            acc[0][2] = __builtin_amdgcn_mfma_f32_16x16x32_bf16(a0, b2, acc[0][2], 0, 0, 0);
            acc[1][2] = __builtin_amdgcn_mfma_f32_16x16x32_bf16(a1, b2, acc[1][2], 0, 0, 0);
            acc[0][3] = __builtin_amdgcn_mfma_f32_16x16x32_bf16(a0, b3, acc[0][3], 0, 0, 0);
            acc[1][3] = __builtin_amdgcn_mfma_f32_16x16x32_bf16(a1, b3, acc[1][3], 0, 0, 0);
        }
    }
    const float* br = bias + r*HID;
    bf16* slab = hp + (size_t)r*HPR + (size_t)b*58*58*64;
    bf16 z = f2b(0.f);
    #pragma unroll
    for (int rr = 0; rr < 2; ++rr){
        int y = y0 + rr;
        bf16* hrow = slab + ((size_t)(y+1)*58 + 1)*64;
        #pragma unroll
        for (int nt = 0; nt < 4; ++nt){
            int oc = nt*16 + m;
            float bv = br[oc];
            #pragma unroll
            for (int r2 = 0; r2 < 4; ++r2){
                int x = x0 + q*4 + r2;
                hrow[(size_t)x*64 + oc] = f2b(fmaxf(acc[rr][nt][r2] + bv, 0.f));
            }
        }
        bf16* rowp = slab + (size_t)(y+1)*58*64;
        if (tid < 64) rowp[tid] = z;
        else if (tid < 128) rowp[57*64 + (tid-64)] = z;
        if (y == 0){ for (int idx = tid; idx < 58*64; idx += 256) slab[idx] = z; }
        if (y == 55){ bf16* r57 = slab + (size_t)57*58*64;
                      for (int idx = tid; idx < 58*64; idx += 256) r57[idx] = z; }
    }
}

// K3: conv2 MFMA implicit GEMM + fused tap-descriptor computation (offsets never touch HBM
// as a separate pass). Grid 896: block = (b, y, r), 18 offset channels -> LDS -> taps.
__global__ __launch_bounds__(256) void k_conv2m(const bf16* __restrict__ hp, const bf16* __restrict__ Bc,
                                                const float* __restrict__ bias, Tap* __restrict__ tap){
    __shared__ float pld[18][56];
    int bx = blockIdx.x; int b = bx & 7; int rid = bx >> 3; int y = rid % 56; int r = rid / 56;
    int tid = threadIdx.x; int wave = tid>>6, lane = tid&63;
    int m = lane&15, q = lane>>4;
    int x0 = (wave==3) ? 40 : wave*16;
    f32x4 acc0 = {0,0,0,0}, acc1 = {0,0,0,0};
    const bf16* Hb = hp + (size_t)r*HPR + ((size_t)b*58 + y)*58*64;
    const bf16* Bcr = Bc + (size_t)r*18*2*64*8;
    #pragma unroll
    for (int t = 0; t < 9; ++t){
        int ty = t/3, tx = t%3;
        const bf16* arow = Hb + ((size_t)ty*58 + (x0+m+tx))*64 + q*8;
        #pragma unroll
        for (int chunk = 0; chunk < 2; ++chunk){
            short8 a = *(const short8*)(arow + chunk*32);
            const bf16* bb = Bcr + (((size_t)(t*2+chunk))*2*64 + lane)*8;
            short8 b0 = *(const short8*)(bb);
            short8 b1 = *(const short8*)(bb + 64*8);
            acc0 = __builtin_amdgcn_mfma_f32_16x16x32_bf16(a, b0, acc0, 0, 0, 0);
            acc1 = __builtin_amdgcn_mfma_f32_16x16x32_bf16(a, b1, acc1, 0, 0, 0);
        }
    }
    const float* br = bias + r*18;
    #pragma unroll
    for (int r2 = 0; r2 < 4; ++r2){
        int x = x0 + q*4 + r2;
        pld[m][x] = acc0[r2] + br[m];                       // overlap x=40..47 writes identical values
        if (m < 2) pld[16+m][x] = acc1[r2] + br[16+m];
    }
    __syncthreads();
    // tap phase: 504 = 9 taps x 56 px
    for (int e = tid; e < 504; e += 256){
        int t = e / 56, x = e % 56;
        int ky = t / 3, kx = t % 3;
        float dy = pld[2*t][x];
        float dx = pld[2*t+1][x];
        float py = (float)(y - 1 + ky) + dy;
        float px = (float)(x - 1 + kx) + dx;
        float y0f = floorf(py), x0f = floorf(px);
        float wy1 = py - y0f, wx1 = px - x0f;
        float wy0 = 1.f - wy1, wx0 = 1.f - wx1;
        float vy0 = (y0f >= 0.f  && y0f <= 55.f) ? 1.f : 0.f;
        float vy1 = (y0f >= -1.f && y0f <= 54.f) ? 1.f : 0.f;
        float vx0 = (x0f >= 0.f  && x0f <= 55.f) ? 1.f : 0.f;
        float vx1 = (x0f >= -1.f && x0f <= 54.f) ? 1.f : 0.f;
        int yy0 = (int)y0f, x0i = (int)x0f;
        int iy0 = min(max(yy0,0),55),   iy1 = min(max(yy0+1,0),55);
        int ix0 = min(max(x0i,0),55),   ix1 = min(max(x0i+1,0),55);
        Tap td;
        td.o00 = ((iy0+1)*58 + ix0+1)*256;
        td.o01 = ((iy0+1)*58 + ix1+1)*256;
        td.o10 = ((iy1+1)*58 + ix0+1)*256;
        td.o11 = ((iy1+1)*58 + ix1+1)*256;
        td.w00 = wy0*wx0*vy0*vx0;
        td.w01 = wy0*wx1*vy0*vx1;
        td.w10 = wy1*wx0*vy1*vx0;
        td.w11 = wy1*wx1*vy1*vx1;
        size_t pid = ((size_t)(r*8 + b))*3136 + y*56 + x;
        tap[pid*9 + t] = td;
    }
}

// K4: merged AKG (pool finish + dwconv3x3 + head matvec + tanh) at FULL 144-block
// parallelism (fixes round-14's 16-block serialization mistake). Each block (r,b,og)
// recomputes its (r,b)'s s[256] in LDS — identical op order to the old k_akg_s, so
// bit-exact; 9x redundant pool work is ~1.6us of L2-resident rowsum reads. Replaces two
// launches (k_akg_s 16 blocks + k_akg_head 144 blocks) and eliminates the s round-trip.
__global__ __launch_bounds__(256) void k_akg(const float* __restrict__ rowsum, const float* __restrict__ dw,
                                             const float* __restrict__ hw, const float* __restrict__ hb,
                                             float* __restrict__ Kw){
    int gid = blockIdx.x; int r = gid / 72; int id = gid % 72;
    int b = id / 9; int og = id % 9;
    int rb = r*8 + b;
    __shared__ float sv[CC_];
    int tid = threadIdx.x;               // 256: channel for pool phase
    {
        int c = tid;
        const float* rs = rowsum + ((size_t)rb*56*7)*256 + c;
        float d[7][7];
        #pragma unroll
        for (int u = 0; u < 7; ++u)
            #pragma unroll
            for (int v = 0; v < 7; ++v){
                float acc = 0.f;
                #pragma unroll
                for (int k = 0; k < 8; ++k) acc += rs[(size_t)((u*8+k)*7 + v)*256];
                d[u][v] = acc * (1.f/64.f);
            }
        const float* wp = dw + (size_t)r*CC_*9 + c*9;
        float w[9];
        #pragma unroll
        for (int k = 0; k < 9; ++k) w[k] = wp[k];
        float tot = 0.f;
        #pragma unroll
        for (int u = 0; u < 7; ++u)
            #pragma unroll
            for (int v = 0; v < 7; ++v){
                float acc = 0.f;
                #pragma unroll
                for (int ky = 0; ky < 3; ++ky){
                    int uu = u+ky-1; if ((unsigned)uu >= 7u) continue;
                    #pragma unroll
                    for (int kx = 0; kx < 3; ++kx){
                        int vv = v+kx-1; if ((unsigned)vv >= 7u) continue;
                        acc += d[uu][vv]*w[ky*3+kx];
                    }
                }
                tot += fmaxf(acc, 0.f);
            }
        sv[c] = tot * (1.f/49.f);
    }
    __syncthreads();
    int o = og*256 + tid;              // o = c*9 + t
    const float* wp = hw + (size_t)r*2304*CC_ + (size_t)o*CC_;
    float acc = hb[(size_t)r*2304 + o];
    for (int c2=0;c2<CC_;++c2) acc += wp[c2]*sv[c2];
    int c = o / 9, t = o - 9*c;
    Kw[((size_t)r*BB + b)*2304 + t*256 + c] = tanhf(acc);
}

// K5: deformable depthwise. v7 EXACT (round-10/13/15/17 verified ~41-43us): swizzled klds
// (stride 76 floats), wave-coop tap bounce, pixel-pair/wave, 8ch/lane 16B gathers, unroll 3.
__global__ __launch_bounds__(256, 8) void k_deform(const bf16* __restrict__ Fp, const Tap* __restrict__ tap,
                                                   const float* __restrict__ Kw, bf16* __restrict__ outsN){
    __shared__ float klds[2432];                 // swizzled: lane li's tap t at [li*76 + t*8 .. +7]
    __shared__ Tap tlds[4][18];                  // per-wave tap bounce (2 px x 9 taps = 576B)
    int bx = blockIdx.x; int b = bx & 7; int rest = bx >> 3;  // rest = creg*392 + pg
    int pg = rest % 392; int creg = rest / 392;
    int tid = threadIdx.x; int w = tid >> 6, l = tid & 63;
    int wu = __builtin_amdgcn_readfirstlane(w);
    int yx0 = pg*8 + wu*2;                       // wave covers pixels yx0, yx0+1
    size_t slab = (size_t)(creg*8 + b)*3136;
    const float* Kb = Kw + ((size_t)creg*8 + b)*2304;
    // stage Kw swizzled: logical Kb[t*256 + c] -> klds[(c>>3)*76 + t*8 + (c&7)]
    for (int i = tid*4; i < 2304; i += 1024){
        f32x4 v = *(const f32x4*)(Kb + i);
        int t = i >> 8, rem = i & 255;
        *(f32x4*)&klds[(rem >> 3)*76 + t*8 + (rem & 4)] = v;
    }
    // wave-cooperative tap bounce: 18 Taps = 36 x 16B lanes
    if (l < 36)
        *(f32x4*)((char*)&tlds[wu][0] + l*16) =
            *(const f32x4*)((const char*)(tap + (slab + yx0)*9) + l*16);
    __syncthreads();
    int h = l >> 5, li = l & 31;
    const bf16* Fb = Fp + (size_t)creg*FPR + (size_t)b*58*58*256;
    int c0 = li*8;                               // 8 channels per lane
    const float* kl = &klds[li*76];
    const Tap* tw = &tlds[wu][h*9];
    float acc[8];
    #pragma unroll
    for (int j = 0; j < 8; ++j) acc[j] = 0.f;
    #pragma unroll 3
    for (int t = 0; t < 9; ++t){
        Tap d = tw[t];
        short8 f00 = *(const short8*)(Fb + d.o00 + c0);
        short8 f01 = *(const short8*)(Fb + d.o01 + c0);
        short8 f10 = *(const short8*)(Fb + d.o10 + c0);
        short8 f11 = *(const short8*)(Fb + d.o11 + c0);
        f32x4 klo = *(const f32x4*)(kl + t*8);
        f32x4 khi = *(const f32x4*)(kl + t*8 + 4);
        #pragma unroll
        for (int j = 0; j < 4; ++j){
            float v = d.w00*bs2f(f00[j]) + d.w01*bs2f(f01[j]) + d.w10*bs2f(f10[j]) + d.w11*bs2f(f11[j]);
            acc[j] += klo[j]*v;
        }
        #pragma unroll
        for (int j = 4; j < 8; ++j){
            float v = d.w00*bs2f(f00[j]) + d.w01*bs2f(f01[j]) + d.w10*bs2f(f10[j]) + d.w11*bs2f(f11[j]);
            acc[j] += khi[j-4]*v;
        }
    }
    __attribute__((aligned(16))) bf16 tmp[8];
    #pragma unroll
    for (int j = 0; j < 8; ++j) tmp[j] = f2b(acc[j]);
    *(short8*)(outsN + ((size_t)b*HWSZ + yx0 + h)*512 + creg*256 + c0) = *(const short8*)tmp;
}

// K6a: pw2 MFMA GEMM, 2 pixel-tiles per wave, stats via LDS reduce + atomics. v18: O stored
// as bf16 (halves O write 25.7->12.9MB; stats stay fp32 from registers). BN error added by
// bf16 rounding of the staging value: ~2e-3 * |z| <= ~0.012 — margin vs 0.114 threshold.
__global__ __launch_bounds__(256) void k_pw2_mstats(const bf16* __restrict__ outsN, const bf16* __restrict__ Bpw,
                                                    const float* __restrict__ bias, float* __restrict__ stats,
                                                    bf16* __restrict__ O){
    __shared__ float ls[2][2][256];
    int tid = threadIdx.x; int wave = tid>>6, lane = tid&63;
    int pixGroup = wave>>1, ntH = wave&1;
    int m = lane&15, q = lane>>4;
    size_t pb = (size_t)blockIdx.x*64 + pixGroup*32;
    const bf16* Ap0 = outsN + (pb + m)*512 + q*8;
    const bf16* Ap1 = Ap0 + (size_t)16*512;
    f32x4 acc[2][8];
    #pragma unroll
    for (int g=0;g<2;++g)
        #pragma unroll
        for (int i=0;i<8;++i) acc[g][i] = (f32x4){0,0,0,0};
    #pragma unroll 1
    for (int kk = 0; kk < 16; ++kk){
        short8 a0 = *(const short8*)(Ap0 + kk*32);
        short8 a1 = *(const short8*)(Ap1 + kk*32);
        const bf16* Bk = Bpw + (((size_t)kk*16 + ntH*8)*64 + lane)*8;
        #pragma unroll
        for (int nt2 = 0; nt2 < 8; ++nt2){
            short8 b = *(const short8*)(Bk + (size_t)nt2*64*8);
            acc[0][nt2] = __builtin_amdgcn_mfma_f32_16x16x32_bf16(a0, b, acc[0][nt2], 0, 0, 0);
            acc[1][nt2] = __builtin_amdgcn_mfma_f32_16x16x32_bf16(a1, b, acc[1][nt2], 0, 0, 0);
        }
    }
    #pragma unroll
    for (int nt2 = 0; nt2 < 8; ++nt2){
        int oc = ntH*128 + nt2*16 + m;
        float bv = bias[oc];
        float s1 = 0.f, s2 = 0.f;
        #pragma unroll
        for (int g = 0; g < 2; ++g){
            size_t pbg = pb + g*16;
            int b_idx = (int)(pbg / HWSZ);
            int yx0 = (int)(pbg % HWSZ);
            bf16* op = O + ((size_t)b_idx*CC_ + oc)*HWSZ + yx0 + q*4;
            __attribute__((aligned(8))) bf16 tm[4];
            #pragma unroll
            for (int r = 0; r < 4; ++r){
                float v = acc[g][nt2][r] + bv;
                tm[r] = f2b(v);
                s1 += v; s2 += v*v;
            }
            *(short4_t*)op = *(const short4_t*)tm;
        }
        s1 += __shfl_down(s1, 32); s1 += __shfl_down(s1, 16);
        s2 += __shfl_down(s2, 32); s2 += __shfl_down(s2, 16);
        if (q == 0){ ls[pixGroup][0][oc] = s1; ls[pixGroup][1][oc] = s2; }
    }
    __syncthreads();
    if (tid < 256){
        atomicAdd(&stats[tid],       ls[0][0][tid] + ls[1][0][tid]);
        atomicAdd(&stats[256 + tid], ls[0][1][tid] + ls[1][1][tid]);
    }
}

// K6b: BN finalize (inline) + apply. v18: reads bf16 O (short4, 8B/lane), writes float4.
__global__ __launch_bounds__(256) void k_bnapply(const bf16* __restrict__ O, const float* __restrict__ stats,
                                                 const float* __restrict__ gamma, const float* __restrict__ beta,
                                                 float* __restrict__ out){
    int n = (blockIdx.x*256 + threadIdx.x)*4;   // HWSZ divisible by 4 -> same channel
    int c = (n / HWSZ) % CC_;
    float ninv = 1.f/(float)NPIX;
    float mean = stats[c]*ninv;
    float var = fmaxf(stats[256+c]*ninv - mean*mean, 0.f);
    float rsq = rsqrtf(var + 1e-5f);
    float g = gamma[c], be = beta[c];
    short4_t v = *(const short4_t*)(O + n);
    f32x4 o;
    #pragma unroll
    for (int j = 0; j < 4; ++j) o[j] = (bs2f(v[j]) - mean)*rsq*g + be;
    *(f32x4*)(out + n) = o;
}

extern "C" void kernel_launch(void* const* d_in, const int* in_sizes, int n_in,
                              void* d_out, int out_size, void* d_ws, size_t ws_size,
                              hipStream_t stream) {
    (void)in_sizes; (void)n_in; (void)out_size; (void)ws_size;
    const float* F_c    = (const float*)d_in[0];
    const float* dec_w  = (const float*)d_in[1];
    const float* dec_b  = (const float*)d_in[2];
    const float* off1_w = (const float*)d_in[3];
    const float* off1_b = (const float*)d_in[4];
    const float* off2_w = (const float*)d_in[5];
    const float* off2_b = (const float*)d_in[6];
    const float* akg_dw = (const float*)d_in[7];
    const float* akg_hw = (const float*)d_in[8];
    const float* akg_hb = (const float*)d_in[9];
    const float* pw2_w  = (const float*)d_in[10];
    const float* pw2_b  = (const float*)d_in[11];
    const float* gamma  = (const float*)d_in[12];
    const float* beta   = (const float*)d_in[13];
    float* out = (float*)d_out;

    char* ws = (char*)d_ws;
    size_t off = 0;
    auto alloc = [&](size_t bytes)->char*{
        char* r = ws + off;
        off = (off + bytes + 255) & ~(size_t)255;
        return r;
    };
    // Workspace ~85 MB.
    bf16*  Fp    = (bf16*) alloc(2*FPR*2);                 // padded NHWC F*sc, both regions
    bf16*  Bp    = (bf16*) alloc((size_t)2*9*16384*2);     // conv1 weight taps (32KB/tap)
    bf16*  Bpw   = (bf16*) alloc((size_t)16*16*64*8*2);    // pw2 weight frags
    bf16*  Bc    = (bf16*) alloc((size_t)2*18*2*64*8*2);   // conv2 weight frags
    float* rowsum= (float*)alloc((size_t)2*8*56*7*256*4);  // AKG pool row partials
    bf16*  hp    = (bf16*) alloc(2*HPR*2);                 // padded NHWC hidden, both regions
    float* Kw    = (float*)alloc((size_t)2*BB*CC_*9*4);
    bf16*  outsN = (bf16*) alloc(NPIX*512*2);              // NHWC, k = creg*256+c
    Tap*   tap   = (Tap*)  alloc((size_t)2*NPIX*9*sizeof(Tap));
    float* stats = (float*)alloc(2*CC_*4);
    // O (bf16, 12.9MB) aliases Fp (27.6MB): Fp is dead after k_deform, O written in k_pw2_mstats.
    bf16* O = Fp;

    hipMemsetAsync(stats, 0, 2*CC_*sizeof(float), stream);

    // scalepack + bprep fused (tail blocks 448..673)
    k_scalepack<<<dim3(448 + 226), dim3(256), 0, stream>>>(F_c, dec_w, dec_b, Fp, rowsum,
                                                           off1_w, pw2_w, off2_w, Bp, Bpw, Bc);
    k_conv1<<<dim3(2*BB*28), dim3(256), 0, stream>>>(Fp, Bp, off1_b, hp);
    k_conv2m<<<dim3(2*BB*HH), dim3(256), 0, stream>>>(hp, Bc, off2_b, tap);
    k_akg<<<dim3(2*BB*9), dim3(256), 0, stream>>>(rowsum, akg_dw, akg_hw, akg_hb, Kw);
    k_deform<<<dim3(2*BB*392), dim3(256), 0, stream>>>(Fp, tap, Kw, outsN);

    k_pw2_mstats<<<dim3(392), dim3(256), 0, stream>>>(outsN, Bpw, pw2_b, stats, O);
    k_bnapply<<<dim3((int)(NPIX*CC_/1024)), dim3(256), 0, stream>>>(O, stats, gamma, beta, out);
}